// Round 18
// baseline (1425.084 us; speedup 1.0000x reference)
//
#include <hip/hip_runtime.h>
#include <math.h>

#define HH 768
#define FF 3072
#define NL 12
#define NH 12
#define DH 64
#define BB 4
#define LL 512
#define SS 8
#define MM (BB*LL)   // 2048
#define WQSZ (HH*HH)
#define W1SZ (HH*FF)
// per-layer transposed-weight block (elems): QKV(2304x768) Wo(768x768) W1(3072x768) W2(768x3072)
// Layout: blocked tiles [kt][nt][64][64] (8 KB each), natural within tile.
#define LWB 7077888
#define OFF_WO 1769472
#define OFF_W1 2359296
#define OFF_W2 4718592

typedef short bf16x8 __attribute__((ext_vector_type(8)));
typedef float f32x4 __attribute__((ext_vector_type(4)));

__device__ inline ushort f2b(float f) {
  unsigned u = __float_as_uint(f);
  unsigned r = (u + 0x7FFFu + ((u >> 16) & 1u)) >> 16;
  return (ushort)r;
}
__device__ inline float b2f(ushort b) {
  return __uint_as_float(((unsigned)b) << 16);
}

// bijective XCD swizzle (m204)
__device__ inline void swz_xy(int& x, int& y) {
  int gx = gridDim.x, gy = gridDim.y;
  int flat = blockIdx.x + blockIdx.y * gx;
  int nwg = gx * gy;
  int q = nwg >> 3, r = nwg & 7;
  int xcd = flat & 7, off = flat >> 3;
  int wgid = (xcd < r ? xcd * (q + 1) : r * (q + 1) + (xcd - r) * q) + off;
  x = wgid / gy; y = wgid - x * gy;
}

// ---------------- prep: valid_len, seg ids ----------------
__global__ void prep_kernel(const int* __restrict__ am, const int* __restrict__ bos,
                            int* __restrict__ seg, int* __restrict__ vl) {
  int b = blockIdx.x;
  int t = threadIdx.x;            // 512 threads
  __shared__ int red[512];
  red[t] = am[b*LL + t];
  __syncthreads();
  for (int off = 256; off > 0; off >>= 1) {
    if (t < off) red[t] += red[t+off];
    __syncthreads();
  }
  if (t == 0) vl[b] = red[0];
  int cnt = 0;
  #pragma unroll
  for (int s = 0; s < SS; s++) cnt += (bos[b*SS + s] <= t) ? 1 : 0;
  seg[b*LL + t] = cnt - 1;
}

// ---------------- embedding + LayerNorm -> bf16 x only ----------------
__global__ __launch_bounds__(256) void embed_ln_kernel(
    const float* __restrict__ word_emb, const float* __restrict__ pos_emb,
    const float* __restrict__ type_emb, const float* __restrict__ g,
    const float* __restrict__ bta, const int* __restrict__ ids,
    const int* __restrict__ tts, ushort* __restrict__ xb)
{
  int row = blockIdx.x;           // 0..2047
  int l = row & (LL-1);
  int t = threadIdx.x;
  int id = ids[row];
  int ty = tts[row];
  float4 v = {0.f,0.f,0.f,0.f};
  float s = 0.f, sq = 0.f;
  int c = t << 2;                 // t<192 active
  if (t < 192) {
    float4 a = *(const float4*)&word_emb[(size_t)id*HH + c];
    float4 p = *(const float4*)&pos_emb[l*HH + c];
    float4 ttv = *(const float4*)&type_emb[ty*HH + c];
    v.x = a.x+p.x+ttv.x; v.y = a.y+p.y+ttv.y; v.z = a.z+p.z+ttv.z; v.w = a.w+p.w+ttv.w;
    s = v.x+v.y+v.z+v.w;
    sq = v.x*v.x+v.y*v.y+v.z*v.z+v.w*v.w;
  }
  __shared__ float rs[256], rq[256];
  rs[t] = s; rq[t] = sq;
  __syncthreads();
  for (int off = 128; off > 0; off >>= 1) {
    if (t < off) { rs[t] += rs[t+off]; rq[t] += rq[t+off]; }
    __syncthreads();
  }
  float mean = rs[0] / HH;
  float var  = rq[0] / HH - mean*mean;
  float inv  = rsqrtf(var + 1e-12f);
  if (t < 192) {
    float4 gv = *(const float4*)&g[c];
    float4 bv = *(const float4*)&bta[c];
    ushort4 ob = { f2b((v.x-mean)*inv*gv.x + bv.x),
                   f2b((v.y-mean)*inv*gv.y + bv.y),
                   f2b((v.z-mean)*inv*gv.z + bv.z),
                   f2b((v.w-mean)*inv*gv.w + bv.w) };
    *(ushort4*)&xb[(size_t)row*HH + c] = ob;
  }
}

// ---------------- bf16 residual + NP bf16 partials + LayerNorm -> bf16 ----------------
template<int NP>
__global__ __launch_bounds__(256) void add_ln_kernel(
    const ushort* __restrict__ xin, const ushort* __restrict__ y,
    const float* __restrict__ g, const float* __restrict__ bta,
    ushort* __restrict__ xb)
{
  int row = blockIdx.x;
  int t = threadIdx.x;
  float4 v = {0.f,0.f,0.f,0.f};
  float s = 0.f, sq = 0.f;
  int c = t << 2;
  size_t ix = (size_t)row*HH + c;
  if (t < 192) {
    ushort4 xv = *(const ushort4*)&xin[ix];
    v.x = b2f(xv.x); v.y = b2f(xv.y); v.z = b2f(xv.z); v.w = b2f(xv.w);
    #pragma unroll
    for (int p = 0; p < NP; p++) {
      ushort4 yv = *(const ushort4*)&y[(size_t)p*MM*HH + ix];
      v.x += b2f(yv.x); v.y += b2f(yv.y); v.z += b2f(yv.z); v.w += b2f(yv.w);
    }
    s = v.x+v.y+v.z+v.w;
    sq = v.x*v.x+v.y*v.y+v.z*v.z+v.w*v.w;
  }
  __shared__ float rs[256], rq[256];
  rs[t] = s; rq[t] = sq;
  __syncthreads();
  for (int off = 128; off > 0; off >>= 1) {
    if (t < off) { rs[t] += rs[t+off]; rq[t] += rq[t+off]; }
    __syncthreads();
  }
  float mean = rs[0] / HH;
  float var  = rq[0] / HH - mean*mean;
  float inv  = rsqrtf(var + 1e-12f);
  if (t < 192) {
    float4 gv = *(const float4*)&g[c];
    float4 bv = *(const float4*)&bta[c];
    ushort4 ob = { f2b((v.x-mean)*inv*gv.x + bv.x),
                   f2b((v.y-mean)*inv*gv.y + bv.y),
                   f2b((v.z-mean)*inv*gv.z + bv.z),
                   f2b((v.w-mean)*inv*gv.w + bv.w) };
    *(ushort4*)&xb[ix] = ob;
  }
}

// ---------------- one-time all-layer weight convert + transpose ----------------
// [kt][nt] blocked-tile output. At traffic roofline (~125 us), parked.
__global__ __launch_bounds__(256) void convw_all_kernel(
    const float* __restrict__ Wq, const float* __restrict__ Wk,
    const float* __restrict__ Wv, const float* __restrict__ Wo,
    const float* __restrict__ W1, const float* __restrict__ W2,
    ushort* __restrict__ wbuf)
{
  int idx = blockIdx.x;           // 0..20735
  int l = idx / 1728;
  int t0 = idx % 1728;
  size_t base = (size_t)l * LWB;
  const float* src; ushort* dst; int Nsrc, NTn, k0, n0src, n0dst;
  if (t0 < 432) {            // QKV fused: 36 n-tiles x 12 k-tiles, nt fastest
    int nt = t0 % 36, kt = t0 / 36;
    int z = nt / 12, ntl = nt % 12;
    src = (z == 0 ? Wq : z == 1 ? Wk : Wv) + (size_t)l*WQSZ;
    dst = wbuf + base;
    Nsrc = HH; NTn = 36; k0 = kt*64; n0src = ntl*64; n0dst = nt*64;
  } else if (t0 < 576) {     // Wo: 12 x 12
    int t = t0 - 432; int nt = t % 12, kt = t / 12;
    src = Wo + (size_t)l*WQSZ;
    dst = wbuf + base + OFF_WO;
    Nsrc = HH; NTn = 12; k0 = kt*64; n0src = n0dst = nt*64;
  } else if (t0 < 1152) {    // W1 (768k x 3072n): 48 x 12
    int t = t0 - 576; int nt = t % 48, kt = t / 48;
    src = W1 + (size_t)l*W1SZ;
    dst = wbuf + base + OFF_W1;
    Nsrc = FF; NTn = 48; k0 = kt*64; n0src = n0dst = nt*64;
  } else {                   // W2 (3072k x 768n): 12 x 48
    int t = t0 - 1152; int nt = t % 12, kt = t / 12;
    src = W2 + (size_t)l*W1SZ;
    dst = wbuf + base + OFF_W2;
    Nsrc = HH; NTn = 12; k0 = kt*64; n0src = n0dst = nt*64;
  }
  __shared__ ushort tt[64][66];   // PAD=66: row stride 132 B
  int tid = threadIdx.x;
  int kr = tid >> 4;              // 0..15
  int nn0 = (tid & 15) << 2;      // 0,4,...,60
  #pragma unroll
  for (int i = 0; i < 4; i++) {
    int k = kr + i*16;
    float4 v = *(const float4*)&src[(size_t)(k0+k)*Nsrc + n0src + nn0];
    ushort2 lo = { f2b(v.x), f2b(v.y) };
    ushort2 hi = { f2b(v.z), f2b(v.w) };
    *(ushort2*)&tt[k][nn0]     = lo;
    *(ushort2*)&tt[k][nn0 + 2] = hi;
  }
  __syncthreads();
  ushort* dtile = dst + ((size_t)(k0 >> 6)*NTn + (n0dst >> 6)) * 4096;
  #pragma unroll
  for (int it = 0; it < 2; it++) {
    int n  = it*32 + (tid >> 3);  // 0..63
    int kc = (tid & 7) << 3;      // 0,8,...,56
    ushort tmp8[8];
    #pragma unroll
    for (int j = 0; j < 8; j++) tmp8[j] = tt[kc + j][n];
    *(uint4*)&dtile[n*64 + kc] = *(const uint4*)tmp8;
  }
}

// ---------------- bf16 MFMA GEMM, 128x64 tile, BK=64, 2-buffer counted-vmcnt pipeline ----------------
// B operand in blocked-tile layout [kt][nt][64][64].
// MODE 0: QKV fused (N=2304), bf16 out split to 3 buffers, per-section bias
// MODE 1: bf16 out + bias + GELU (FF1)
// MODE 2: bf16 partial out (splitK4 via blockIdx.z), bias at z==0 (Wo, FF2)
template<int MODE>
__global__ __launch_bounds__(256) void gemm_bt(
    const ushort* __restrict__ A, const ushort* __restrict__ Bt,
    const float* __restrict__ ba, const float* __restrict__ bb,
    const float* __restrict__ bc, ushort* __restrict__ Cb,
    int M, int N, int K)
{
  __shared__ __align__(16) ushort As[2][128*64];
  __shared__ __align__(16) ushort Bs[2][64*64];
  const int tid = threadIdx.x;
  const int lane = tid & 63, wid = tid >> 6;
  const int wm = wid >> 1, wn = wid & 1;
  int bx, by; swz_xy(bx, by);
  const int m0 = by * 128, n0 = bx * 64;
  int kbeg = 0, kcnt = K;
  if (MODE == 2) { kcnt = K >> 2; kbeg = blockIdx.z * kcnt; }
  const int NT = kcnt >> 6;
  const int ntiles = N >> 6;

  auto STAGE = [&](int buf, int k0) {
    #pragma unroll
    for (int j = 0; j < 4; j++) {
      int c = j*256 + tid;
      int r = c >> 3;
      int kk = ((c & 7) ^ (r & 7)) << 3;
      __builtin_amdgcn_global_load_lds(
        (const __attribute__((address_space(1))) void*)(A + (size_t)(m0+r)*K + k0 + kk),
        (__attribute__((address_space(3))) void*)(&As[buf][c*8]), 16, 0, 0);
    }
    const ushort* btile = Bt + ((size_t)(k0 >> 6) * ntiles + (n0 >> 6)) * 4096;
    #pragma unroll
    for (int j = 0; j < 2; j++) {
      int c = j*256 + tid;
      int r = c >> 3;
      int kk = ((c & 7) ^ (r & 7)) << 3;
      __builtin_amdgcn_global_load_lds(
        (const __attribute__((address_space(1))) void*)(btile + r*64 + kk),
        (__attribute__((address_space(3))) void*)(&Bs[buf][c*8]), 16, 0, 0);
    }
  };

  f32x4 acc[4][2] = {};
  STAGE(0, kbeg);
  if (NT > 1) STAGE(1, kbeg + 64);
  for (int t = 0; t < NT; ++t) {
    const int cur = t & 1;
    if (t + 1 < NT) asm volatile("s_waitcnt vmcnt(6)" ::: "memory");
    else            asm volatile("s_waitcnt vmcnt(0)" ::: "memory");
    __builtin_amdgcn_sched_barrier(0);
    __builtin_amdgcn_s_barrier();
    __builtin_amdgcn_sched_barrier(0);

    bf16x8 af[4][2], bfv[2][2];
    #pragma unroll
    for (int mi = 0; mi < 4; mi++) {
      int row = wm*64 + mi*16 + (lane & 15);
      #pragma unroll
      for (int ks = 0; ks < 2; ks++) {
        int kb = (ks*64 + ((lane >> 4) << 4)) ^ ((row & 7) << 4);
        af[mi][ks] = *(const bf16x8*)((const char*)&As[cur][0] + row*128 + kb);
      }
    }
    #pragma unroll
    for (int ni = 0; ni < 2; ni++) {
      int row = wn*32 + ni*16 + (lane & 15);
      #pragma unroll
      for (int ks = 0; ks < 2; ks++) {
        int kb = (ks*64 + ((lane >> 4) << 4)) ^ ((row & 7) << 4);
        bfv[ni][ks] = *(const bf16x8*)((const char*)&Bs[cur][0] + row*128 + kb);
      }
    }
    #pragma unroll
    for (int ks = 0; ks < 2; ks++)
      #pragma unroll
      for (int mi = 0; mi < 4; mi++)
        #pragma unroll
        for (int ni = 0; ni < 2; ni++)
          acc[mi][ni] = __builtin_amdgcn_mfma_f32_16x16x32_bf16(af[mi][ks], bfv[ni][ks], acc[mi][ni], 0, 0, 0);

    asm volatile("s_waitcnt lgkmcnt(0)" ::: "memory");
    __builtin_amdgcn_sched_barrier(0);
    __builtin_amdgcn_s_barrier();
    __builtin_amdgcn_sched_barrier(0);
    if (t + 2 < NT) STAGE(cur, kbeg + (t + 2) * 64);
  }

  #pragma unroll
  for (int mi = 0; mi < 4; mi++) {
    #pragma unroll
    for (int ni = 0; ni < 2; ni++) {
      int col = n0 + wn*32 + ni*16 + (lane & 15);
      if (MODE == 0) {
        int z = n0 / 768;            // section uniform per block (2304 = 36*64)
        int cc = col - z*768;
        float bvv = (z == 0 ? ba : z == 1 ? bb : bc)[cc];
        #pragma unroll
        for (int r = 0; r < 4; r++) {
          int row = m0 + wm*64 + mi*16 + (lane >> 4)*4 + r;
          Cb[(size_t)z*MM*HH + (size_t)row*HH + cc] = f2b(acc[mi][ni][r] + bvv);
        }
      } else if (MODE == 1) {
        float bvv = ba[col];
        #pragma unroll
        for (int r = 0; r < 4; r++) {
          int row = m0 + wm*64 + mi*16 + (lane >> 4)*4 + r;
          float v = acc[mi][ni][r] + bvv;
          v = 0.5f * v * (1.0f + erff(v * 0.70710678118654752f));
          Cb[(size_t)row*N + col] = f2b(v);
        }
      } else {
        float bvv = (blockIdx.z == 0) ? ba[col] : 0.f;
        #pragma unroll
        for (int r = 0; r < 4; r++) {
          int row = m0 + wm*64 + mi*16 + (lane >> 4)*4 + r;
          Cb[(size_t)blockIdx.z*M*N + (size_t)row*N + col] = f2b(acc[mi][ni][r] + bvv);
        }
      }
    }
  }
}

// ---------------- MFMA flash attention: 2 waves/block, QBLK=32, dbuf + defer-max ----------------
// grid (LL/32, NH, BB) = 768 blocks of 128 threads -> 3 blocks/CU, staging of one
// block overlaps compute of another; per-k-tile barrier syncs only 2 waves.
__global__ __launch_bounds__(128) void attn_mfma_kernel(
    const ushort* __restrict__ Q, const ushort* __restrict__ Kp, const ushort* __restrict__ Vp,
    ushort* __restrict__ ctx, const int* __restrict__ seg, const int* __restrict__ vl,
    const int* __restrict__ bos)
{
  const int q0 = blockIdx.x * 32;
  const int h  = blockIdx.y;
  const int b  = blockIdx.z;
  const int tid = threadIdx.x;    // 0..127
  const int lane = tid & 63;
  const int wid = tid >> 6;       // 0..1

  __shared__ __align__(16) char Ks[2][8192];
  __shared__ __align__(16) char Vt[2][8192];
  __shared__ __align__(16) char Ps[2][2048];
  __shared__ int segk[2][64];

  const int qrow_frag = q0 + wid*16 + (lane & 15);
  bf16x8 qf[2];
  #pragma unroll
  for (int c = 0; c < 2; c++)
    qf[c] = *(const bf16x8*)&Q[((size_t)(b*LL + qrow_frag))*HH + h*DH + 32*c + (lane >> 4)*8];

  const int vlb  = vl[b];
  const int hist = bos[b*SS];
  int segq[4]; bool qvalid[4], qhist[4];
  #pragma unroll
  for (int r = 0; r < 4; r++) {
    int qg = q0 + wid*16 + (lane >> 4)*4 + r;
    segq[r]   = seg[b*LL + qg];
    qvalid[r] = qg < vlb;
    qhist[r]  = qg < hist;
  }

  float mrow[4], lrow[4];
  #pragma unroll
  for (int r = 0; r < 4; r++) { mrow[r] = -1e30f; lrow[r] = 0.f; }
  f32x4 Oacc[4] = {};

  uint4 kreg[4], vreg[4];
  int sreg = 0;

  // 128 threads: K rows rk,rk+16,rk+32,rk+48 (rk=tid>>3, c8=(tid&7)*8);
  // V: k=lane, d-chunks wid*8 + p*16.
  auto LOADT = [&](int k0) {
    int rk = tid >> 3;
    int c8 = (tid & 7) * 8;
    #pragma unroll
    for (int p = 0; p < 4; p++)
      kreg[p] = *(const uint4*)&Kp[((size_t)(b*LL + k0 + rk + p*16))*HH + h*DH + c8];
    #pragma unroll
    for (int p = 0; p < 4; p++)
      vreg[p] = *(const uint4*)&Vp[((size_t)(b*LL + k0 + lane))*HH + h*DH + wid*8 + p*16];
    if (tid < 64) sreg = seg[b*LL + k0 + tid];
  };
  auto STORET = [&](int buf) {
    int rk = tid >> 3;
    int c8 = (tid & 7) * 8;
    #pragma unroll
    for (int p = 0; p < 4; p++) {
      int r = rk + p*16;
      *(uint4*)(Ks[buf] + (r*128 + ((c8*2) ^ ((r & 7) << 4)))) = kreg[p];
    }
    #pragma unroll
    for (int p = 0; p < 4; p++) {
      const ushort* pv = (const ushort*)&vreg[p];
      #pragma unroll
      for (int j = 0; j < 8; j++) {
        int d = wid*8 + p*16 + j;
        *(ushort*)(Vt[buf] + (d*128 + ((lane*2) ^ ((d & 7) << 4)))) = pv[j];
      }
    }
    if (tid < 64) segk[buf][tid] = sreg;
  };

  LOADT(0);
  STORET(0);
  __syncthreads();

  for (int kt = 0; kt < 8; kt++) {
    const int cur = kt & 1;
    const int k0 = kt * 64;
    if (kt < 7) LOADT(k0 + 64);           // issue next-tile loads early
    __builtin_amdgcn_sched_barrier(0);

    // ---- S = Q K^T ----
    f32x4 sacc[4] = {};
    #pragma unroll
    for (int t = 0; t < 4; t++) {
      int krow = (lane & 15) + 16*t;
      #pragma unroll
      for (int c = 0; c < 2; c++) {
        bf16x8 kf = *(const bf16x8*)(Ks[cur] + (krow*128 +
                      (((32*c + (lane >> 4)*8)*2) ^ ((krow & 7) << 4))));
        sacc[t] = __builtin_amdgcn_mfma_f32_16x16x32_bf16(qf[c], kf, sacc[t], 0, 0, 0);
      }
    }

    // ---- scale + mask ----
    #pragma unroll
    for (int t = 0; t < 4; t++) {
      int kg = k0 + (lane & 15) + 16*t;
      bool kvalid = kg < vlb;
      bool khist  = kg < hist;
      int  sk     = segk[cur][(lane & 15) + 16*t];
      #pragma unroll
      for (int r = 0; r < 4; r++) {
        bool ok = qvalid[r] && kvalid && (khist || qhist[r] || (segq[r] == sk));
        sacc[t][r] = sacc[t][r]*0.125f + (ok ? 0.f : -10000.f);
      }
    }

    // ---- online softmax with defer-max (THR=8) ----
    float scl[4];
    #pragma unroll
    for (int r = 0; r < 4; r++) {
      float rm = fmaxf(fmaxf(sacc[0][r], sacc[1][r]), fmaxf(sacc[2][r], sacc[3][r]));
      rm = fmaxf(rm, __shfl_xor(rm, 1));
      rm = fmaxf(rm, __shfl_xor(rm, 2));
      rm = fmaxf(rm, __shfl_xor(rm, 4));
      rm = fmaxf(rm, __shfl_xor(rm, 8));
      float mnew = (rm > mrow[r] + 8.f) ? rm : mrow[r];
      scl[r] = (mnew == mrow[r]) ? 1.f : __expf(mrow[r] - mnew);
      float rsum = 0.f;
      #pragma unroll
      for (int t = 0; t < 4; t++) {
        float p = __expf(sacc[t][r] - mnew);
        sacc[t][r] = p;
        rsum += p;
      }
      rsum += __shfl_xor(rsum, 1);
      rsum += __shfl_xor(rsum, 2);
      rsum += __shfl_xor(rsum, 4);
      rsum += __shfl_xor(rsum, 8);
      mrow[r] = mnew;
      lrow[r] = lrow[r]*scl[r] + rsum;
    }

    // ---- P -> bf16 -> per-wave LDS -> A-layout fragments ----
    char* Pl = Ps[wid];
    #pragma unroll
    for (int t = 0; t < 4; t++) {
      #pragma unroll
      for (int r = 0; r < 4; r++) {
        int q = (lane >> 4)*4 + r;
        int k = (lane & 15) + 16*t;
        *(ushort*)(Pl + (q*128 + ((k*2) ^ ((q & 7) << 4)))) = f2b(sacc[t][r]);
      }
    }
    asm volatile("s_waitcnt lgkmcnt(0)" ::: "memory");
    bf16x8 pf[2];
    #pragma unroll
    for (int c = 0; c < 2; c++) {
      int q = lane & 15;
      int k = 32*c + (lane >> 4)*8;
      pf[c] = *(const bf16x8*)(Pl + (q*128 + ((k*2) ^ ((q & 7) << 4))));
    }

    // ---- O = O*scl + P V ----
    bool needscale = (scl[0] != 1.f) | (scl[1] != 1.f) | (scl[2] != 1.f) | (scl[3] != 1.f);
    #pragma unroll
    for (int nt = 0; nt < 4; nt++) {
      if (needscale) {
        #pragma unroll
        for (int r = 0; r < 4; r++) Oacc[nt][r] *= scl[r];
      }
      int d = (lane & 15) + 16*nt;
      #pragma unroll
      for (int c = 0; c < 2; c++) {
        int k = 32*c + (lane >> 4)*8;
        bf16x8 vf = *(const bf16x8*)(Vt[cur] + (d*128 + ((k*2) ^ ((d & 7) << 4))));
        Oacc[nt] = __builtin_amdgcn_mfma_f32_16x16x32_bf16(pf[c], vf, Oacc[nt], 0, 0, 0);
      }
    }

    if (kt < 7) STORET(cur ^ 1);          // write prefetched tile (waits its vmcnt)
    __syncthreads();
  }

  #pragma unroll
  for (int nt = 0; nt < 4; nt++) {
    #pragma unroll
    for (int r = 0; r < 4; r++) {
      int q = q0 + wid*16 + (lane >> 4)*4 + r;
      int d = h*DH + (lane & 15) + 16*nt;
      ctx[(size_t)(b*LL + q)*HH + d] = f2b(Oacc[nt][r] / lrow[r]);
    }
  }
}

// ---------------- final pooling (bf16 x) ----------------
__global__ __launch_bounds__(256) void rowdot_kernel(const ushort* __restrict__ x,
                                                     const float* __restrict__ w,
                                                     float* __restrict__ rd) {
  int row = blockIdx.x;
  int t = threadIdx.x;
  float s = 0.f;
  if (t < 192) {
    int c = t << 2;
    ushort4 xv = *(const ushort4*)&x[(size_t)row*HH + c];
    float4 wv = *(const float4*)&w[c];
    s = b2f(xv.x)*wv.x + b2f(xv.y)*wv.y + b2f(xv.z)*wv.z + b2f(xv.w)*wv.w;
  }
  __shared__ float red[256];
  red[t] = s;
  __syncthreads();
  for (int off = 128; off > 0; off >>= 1) {
    if (t < off) red[t] += red[t+off];
    __syncthreads();
  }
  if (t == 0) rd[row] = red[0];
}

__global__ void logits_kernel(const float* __restrict__ rd, const int* __restrict__ bos,
                              const int* __restrict__ vl, const float* __restrict__ fcb,
                              float* __restrict__ out) {
  int i = threadIdx.x;
  if (i >= BB*SS) return;
  int b = i / SS, s = i % SS;
  int start = bos[b*SS + s];
  int end   = (s == SS-1) ? vl[b] : bos[b*SS + s + 1];
  float sum = 0.f;
  for (int t = start; t < end; t++) sum += rd[b*LL + t];
  out[i] = sum / (float)(end - start) + fcb[0];
}

extern "C" void kernel_launch(void* const* d_in, const int* in_sizes, int n_in,
                              void* d_out, int out_size, void* d_ws, size_t ws_size,
                              hipStream_t stream) {
  const float* word_emb  = (const float*)d_in[0];
  const float* pos_emb   = (const float*)d_in[1];
  const float* type_emb  = (const float*)d_in[2];
  const float* emb_ln_g  = (const float*)d_in[3];
  const float* emb_ln_b  = (const float*)d_in[4];
  const float* Wq        = (const float*)d_in[5];
  const float* bq        = (const float*)d_in[6];
  const float* Wk        = (const float*)d_in[7];
  const float* bk        = (const float*)d_in[8];
  const float* Wv        = (const float*)d_in[9];
  const float* bv        = (const float*)d_in[10];
  const float* Wo        = (const float*)d_in[11];
  const float* bo        = (const float*)d_in[12];
  const float* attn_ln_g = (const float*)d_in[13];
  const float* attn_ln_b = (const float*)d_in[14];
  const float* W1        = (const float*)d_in[15];
  const float* b1        = (const float*)d_in[16];
  const float* W2        = (const float*)d_in[17];
  const float* b2        = (const float*)d_in[18];
  const float* ffn_ln_g  = (const float*)d_in[19];
  const float* ffn_ln_b  = (const float*)d_in[20];
  const float* fc_w      = (const float*)d_in[21];
  const float* fc_b      = (const float*)d_in[22];
  const int* input_ids   = (const int*)d_in[23];
  const int* token_type  = (const int*)d_in[24];
  const int* am          = (const int*)d_in[25];
  const int* bos         = (const int*)d_in[26];
  float* out = (float*)d_out;

  char* w = (char*)d_ws;
  ushort* tmpb    = (ushort*)w; w += (size_t)4*MM*HH*2;   // 4 split-K bf16 partials
  ushort* qkv_bf  = (ushort*)w; w += (size_t)3*MM*HH*2;
  ushort* x_bf    = (ushort*)w; w += (size_t)MM*HH*2;
  ushort* ctx_bf  = (ushort*)w; w += (size_t)MM*HH*2;
  ushort* hbuf_bf = (ushort*)w; w += (size_t)MM*FF*2;
  ushort* wbuf    = (ushort*)w; w += (size_t)NL*LWB*2;    // all-layer bf16 weights (blocked tiles)
  float*  rd      = (float*)w;  w += (size_t)MM*4;
  int*    seg     = (int*)w;    w += (size_t)MM*4;
  int*    vl      = (int*)w;    w += 64;

  prep_kernel<<<BB, 512, 0, stream>>>(am, bos, seg, vl);
  convw_all_kernel<<<NL*1728, 256, 0, stream>>>(Wq, Wk, Wv, Wo, W1, W2, wbuf);
  embed_ln_kernel<<<MM, 256, 0, stream>>>(word_emb, pos_emb, type_emb,
                                          emb_ln_g, emb_ln_b, input_ids, token_type, x_bf);

  dim3 gqkv(2304/64, MM/128);       // 36 x 16 = 576 blocks
  dim3 g_ff1(FF/64, MM/128);        // 48 x 16 = 768 blocks
  dim3 g_sk(HH/64, MM/128, 4);      // 12 x 16 x 4 = 768 blocks (split-K4)
  dim3 gattn(LL/32, NH, BB);        // 16 x 12 x 4 = 768 blocks of 128 threads

  for (int l = 0; l < NL; l++) {
    const ushort* Wqkv_t = wbuf + (size_t)l*LWB;
    const ushort* Wo_t   = wbuf + (size_t)l*LWB + OFF_WO;
    const ushort* W1_t   = wbuf + (size_t)l*LWB + OFF_W1;
    const ushort* W2_t   = wbuf + (size_t)l*LWB + OFF_W2;

    gemm_bt<0><<<gqkv, 256, 0, stream>>>(x_bf, Wqkv_t,
        bq + (size_t)l*HH, bk + (size_t)l*HH, bv + (size_t)l*HH,
        qkv_bf, MM, 2304, HH);

    attn_mfma_kernel<<<gattn, 128, 0, stream>>>(qkv_bf, qkv_bf + (size_t)MM*HH,
                                                qkv_bf + (size_t)2*MM*HH, ctx_bf, seg, vl, bos);

    gemm_bt<2><<<g_sk, 256, 0, stream>>>(ctx_bf, Wo_t,
        bo + (size_t)l*HH, nullptr, nullptr, tmpb, MM, HH, HH);

    add_ln_kernel<4><<<MM, 256, 0, stream>>>(x_bf, tmpb, attn_ln_g + (size_t)l*HH,
                                             attn_ln_b + (size_t)l*HH, x_bf);

    gemm_bt<1><<<g_ff1, 256, 0, stream>>>(x_bf, W1_t,
        b1 + (size_t)l*FF, nullptr, nullptr, hbuf_bf, MM, FF, HH);

    gemm_bt<2><<<g_sk, 256, 0, stream>>>(hbuf_bf, W2_t,
        b2 + (size_t)l*HH, nullptr, nullptr, tmpb, MM, HH, FF);

    add_ln_kernel<4><<<MM, 256, 0, stream>>>(x_bf, tmpb, ffn_ln_g + (size_t)l*HH,
                                             ffn_ln_b + (size_t)l*HH, x_bf);
  }

  rowdot_kernel<<<MM, 256, 0, stream>>>(x_bf, fc_w, rd);
  logits_kernel<<<1, 64, 0, stream>>>(rd, bos, vl, fc_b, out);
}

// Round 19
// 1336.921 us; speedup vs baseline: 1.0659x; 1.0659x over previous
//
#include <hip/hip_runtime.h>
#include <math.h>

#define HH 768
#define FF 3072
#define NL 12
#define NH 12
#define DH 64
#define BB 4
#define LL 512
#define SS 8
#define MM (BB*LL)   // 2048
#define WQSZ (HH*HH)
#define W1SZ (HH*FF)
// per-layer transposed-weight block (elems): QKV(2304x768) Wo(768x768) W1(3072x768) W2(768x3072)
// Layout: blocked tiles [kt][nt][64][64] (8 KB each), natural within tile.
#define LWB 7077888
#define OFF_WO 1769472
#define OFF_W1 2359296
#define OFF_W2 4718592

typedef short bf16x8 __attribute__((ext_vector_type(8)));
typedef float f32x4 __attribute__((ext_vector_type(4)));

__device__ inline ushort f2b(float f) {
  unsigned u = __float_as_uint(f);
  unsigned r = (u + 0x7FFFu + ((u >> 16) & 1u)) >> 16;
  return (ushort)r;
}
__device__ inline float b2f(ushort b) {
  return __uint_as_float(((unsigned)b) << 16);
}

// bijective XCD swizzle (m204)
__device__ inline void swz_xy(int& x, int& y) {
  int gx = gridDim.x, gy = gridDim.y;
  int flat = blockIdx.x + blockIdx.y * gx;
  int nwg = gx * gy;
  int q = nwg >> 3, r = nwg & 7;
  int xcd = flat & 7, off = flat >> 3;
  int wgid = (xcd < r ? xcd * (q + 1) : r * (q + 1) + (xcd - r) * q) + off;
  x = wgid / gy; y = wgid - x * gy;
}

// ---------------- prep: valid_len, seg ids ----------------
__global__ void prep_kernel(const int* __restrict__ am, const int* __restrict__ bos,
                            int* __restrict__ seg, int* __restrict__ vl) {
  int b = blockIdx.x;
  int t = threadIdx.x;            // 512 threads
  __shared__ int red[512];
  red[t] = am[b*LL + t];
  __syncthreads();
  for (int off = 256; off > 0; off >>= 1) {
    if (t < off) red[t] += red[t+off];
    __syncthreads();
  }
  if (t == 0) vl[b] = red[0];
  int cnt = 0;
  #pragma unroll
  for (int s = 0; s < SS; s++) cnt += (bos[b*SS + s] <= t) ? 1 : 0;
  seg[b*LL + t] = cnt - 1;
}

// ---------------- embedding + LayerNorm -> bf16 x only ----------------
__global__ __launch_bounds__(256) void embed_ln_kernel(
    const float* __restrict__ word_emb, const float* __restrict__ pos_emb,
    const float* __restrict__ type_emb, const float* __restrict__ g,
    const float* __restrict__ bta, const int* __restrict__ ids,
    const int* __restrict__ tts, ushort* __restrict__ xb)
{
  int row = blockIdx.x;           // 0..2047
  int l = row & (LL-1);
  int t = threadIdx.x;
  int id = ids[row];
  int ty = tts[row];
  float4 v = {0.f,0.f,0.f,0.f};
  float s = 0.f, sq = 0.f;
  int c = t << 2;                 // t<192 active
  if (t < 192) {
    float4 a = *(const float4*)&word_emb[(size_t)id*HH + c];
    float4 p = *(const float4*)&pos_emb[l*HH + c];
    float4 ttv = *(const float4*)&type_emb[ty*HH + c];
    v.x = a.x+p.x+ttv.x; v.y = a.y+p.y+ttv.y; v.z = a.z+p.z+ttv.z; v.w = a.w+p.w+ttv.w;
    s = v.x+v.y+v.z+v.w;
    sq = v.x*v.x+v.y*v.y+v.z*v.z+v.w*v.w;
  }
  __shared__ float rs[256], rq[256];
  rs[t] = s; rq[t] = sq;
  __syncthreads();
  for (int off = 128; off > 0; off >>= 1) {
    if (t < off) { rs[t] += rs[t+off]; rq[t] += rq[t+off]; }
    __syncthreads();
  }
  float mean = rs[0] / HH;
  float var  = rq[0] / HH - mean*mean;
  float inv  = rsqrtf(var + 1e-12f);
  if (t < 192) {
    float4 gv = *(const float4*)&g[c];
    float4 bv = *(const float4*)&bta[c];
    ushort4 ob = { f2b((v.x-mean)*inv*gv.x + bv.x),
                   f2b((v.y-mean)*inv*gv.y + bv.y),
                   f2b((v.z-mean)*inv*gv.z + bv.z),
                   f2b((v.w-mean)*inv*gv.w + bv.w) };
    *(ushort4*)&xb[(size_t)row*HH + c] = ob;
  }
}

// ---------------- bf16 residual + NP bf16 partials + LayerNorm -> bf16 ----------------
template<int NP>
__global__ __launch_bounds__(256) void add_ln_kernel(
    const ushort* __restrict__ xin, const ushort* __restrict__ y,
    const float* __restrict__ g, const float* __restrict__ bta,
    ushort* __restrict__ xb)
{
  int row = blockIdx.x;
  int t = threadIdx.x;
  float4 v = {0.f,0.f,0.f,0.f};
  float s = 0.f, sq = 0.f;
  int c = t << 2;
  size_t ix = (size_t)row*HH + c;
  if (t < 192) {
    ushort4 xv = *(const ushort4*)&xin[ix];
    v.x = b2f(xv.x); v.y = b2f(xv.y); v.z = b2f(xv.z); v.w = b2f(xv.w);
    #pragma unroll
    for (int p = 0; p < NP; p++) {
      ushort4 yv = *(const ushort4*)&y[(size_t)p*MM*HH + ix];
      v.x += b2f(yv.x); v.y += b2f(yv.y); v.z += b2f(yv.z); v.w += b2f(yv.w);
    }
    s = v.x+v.y+v.z+v.w;
    sq = v.x*v.x+v.y*v.y+v.z*v.z+v.w*v.w;
  }
  __shared__ float rs[256], rq[256];
  rs[t] = s; rq[t] = sq;
  __syncthreads();
  for (int off = 128; off > 0; off >>= 1) {
    if (t < off) { rs[t] += rs[t+off]; rq[t] += rq[t+off]; }
    __syncthreads();
  }
  float mean = rs[0] / HH;
  float var  = rq[0] / HH - mean*mean;
  float inv  = rsqrtf(var + 1e-12f);
  if (t < 192) {
    float4 gv = *(const float4*)&g[c];
    float4 bv = *(const float4*)&bta[c];
    ushort4 ob = { f2b((v.x-mean)*inv*gv.x + bv.x),
                   f2b((v.y-mean)*inv*gv.y + bv.y),
                   f2b((v.z-mean)*inv*gv.z + bv.z),
                   f2b((v.w-mean)*inv*gv.w + bv.w) };
    *(ushort4*)&xb[ix] = ob;
  }
}

// ---------------- one-time all-layer weight convert + transpose ----------------
// [kt][nt] blocked-tile output. At traffic roofline (~125 us), parked.
__global__ __launch_bounds__(256) void convw_all_kernel(
    const float* __restrict__ Wq, const float* __restrict__ Wk,
    const float* __restrict__ Wv, const float* __restrict__ Wo,
    const float* __restrict__ W1, const float* __restrict__ W2,
    ushort* __restrict__ wbuf)
{
  int idx = blockIdx.x;           // 0..20735
  int l = idx / 1728;
  int t0 = idx % 1728;
  size_t base = (size_t)l * LWB;
  const float* src; ushort* dst; int Nsrc, NTn, k0, n0src, n0dst;
  if (t0 < 432) {            // QKV fused: 36 n-tiles x 12 k-tiles, nt fastest
    int nt = t0 % 36, kt = t0 / 36;
    int z = nt / 12, ntl = nt % 12;
    src = (z == 0 ? Wq : z == 1 ? Wk : Wv) + (size_t)l*WQSZ;
    dst = wbuf + base;
    Nsrc = HH; NTn = 36; k0 = kt*64; n0src = ntl*64; n0dst = nt*64;
  } else if (t0 < 576) {     // Wo: 12 x 12
    int t = t0 - 432; int nt = t % 12, kt = t / 12;
    src = Wo + (size_t)l*WQSZ;
    dst = wbuf + base + OFF_WO;
    Nsrc = HH; NTn = 12; k0 = kt*64; n0src = n0dst = nt*64;
  } else if (t0 < 1152) {    // W1 (768k x 3072n): 48 x 12
    int t = t0 - 576; int nt = t % 48, kt = t / 48;
    src = W1 + (size_t)l*W1SZ;
    dst = wbuf + base + OFF_W1;
    Nsrc = FF; NTn = 48; k0 = kt*64; n0src = n0dst = nt*64;
  } else {                   // W2 (3072k x 768n): 12 x 48
    int t = t0 - 1152; int nt = t % 12, kt = t / 12;
    src = W2 + (size_t)l*W1SZ;
    dst = wbuf + base + OFF_W2;
    Nsrc = HH; NTn = 12; k0 = kt*64; n0src = n0dst = nt*64;
  }
  __shared__ ushort tt[64][66];   // PAD=66: row stride 132 B
  int tid = threadIdx.x;
  int kr = tid >> 4;              // 0..15
  int nn0 = (tid & 15) << 2;      // 0,4,...,60
  #pragma unroll
  for (int i = 0; i < 4; i++) {
    int k = kr + i*16;
    float4 v = *(const float4*)&src[(size_t)(k0+k)*Nsrc + n0src + nn0];
    ushort2 lo = { f2b(v.x), f2b(v.y) };
    ushort2 hi = { f2b(v.z), f2b(v.w) };
    *(ushort2*)&tt[k][nn0]     = lo;
    *(ushort2*)&tt[k][nn0 + 2] = hi;
  }
  __syncthreads();
  ushort* dtile = dst + ((size_t)(k0 >> 6)*NTn + (n0dst >> 6)) * 4096;
  #pragma unroll
  for (int it = 0; it < 2; it++) {
    int n  = it*32 + (tid >> 3);  // 0..63
    int kc = (tid & 7) << 3;      // 0,8,...,56
    ushort tmp8[8];
    #pragma unroll
    for (int j = 0; j < 8; j++) tmp8[j] = tt[kc + j][n];
    *(uint4*)&dtile[n*64 + kc] = *(const uint4*)tmp8;
  }
}

// ---------------- bf16 MFMA GEMM, 128x64 tile, BK=64, 2-buffer counted-vmcnt pipeline ----------------
// B operand in blocked-tile layout [kt][nt][64][64].
// MODE 0: QKV fused (N=2304), bf16 out split to 3 buffers, per-section bias
// MODE 1: bf16 out + bias + GELU (FF1)
// MODE 2: bf16 partial out (splitK4 via blockIdx.z), bias at z==0 (Wo, FF2)
template<int MODE>
__global__ __launch_bounds__(256) void gemm_bt(
    const ushort* __restrict__ A, const ushort* __restrict__ Bt,
    const float* __restrict__ ba, const float* __restrict__ bb,
    const float* __restrict__ bc, ushort* __restrict__ Cb,
    int M, int N, int K)
{
  __shared__ __align__(16) ushort As[2][128*64];
  __shared__ __align__(16) ushort Bs[2][64*64];
  const int tid = threadIdx.x;
  const int lane = tid & 63, wid = tid >> 6;
  const int wm = wid >> 1, wn = wid & 1;
  int bx, by; swz_xy(bx, by);
  const int m0 = by * 128, n0 = bx * 64;
  int kbeg = 0, kcnt = K;
  if (MODE == 2) { kcnt = K >> 2; kbeg = blockIdx.z * kcnt; }
  const int NT = kcnt >> 6;
  const int ntiles = N >> 6;

  auto STAGE = [&](int buf, int k0) {
    #pragma unroll
    for (int j = 0; j < 4; j++) {
      int c = j*256 + tid;
      int r = c >> 3;
      int kk = ((c & 7) ^ (r & 7)) << 3;
      __builtin_amdgcn_global_load_lds(
        (const __attribute__((address_space(1))) void*)(A + (size_t)(m0+r)*K + k0 + kk),
        (__attribute__((address_space(3))) void*)(&As[buf][c*8]), 16, 0, 0);
    }
    const ushort* btile = Bt + ((size_t)(k0 >> 6) * ntiles + (n0 >> 6)) * 4096;
    #pragma unroll
    for (int j = 0; j < 2; j++) {
      int c = j*256 + tid;
      int r = c >> 3;
      int kk = ((c & 7) ^ (r & 7)) << 3;
      __builtin_amdgcn_global_load_lds(
        (const __attribute__((address_space(1))) void*)(btile + r*64 + kk),
        (__attribute__((address_space(3))) void*)(&Bs[buf][c*8]), 16, 0, 0);
    }
  };

  f32x4 acc[4][2] = {};
  STAGE(0, kbeg);
  if (NT > 1) STAGE(1, kbeg + 64);
  for (int t = 0; t < NT; ++t) {
    const int cur = t & 1;
    if (t + 1 < NT) asm volatile("s_waitcnt vmcnt(6)" ::: "memory");
    else            asm volatile("s_waitcnt vmcnt(0)" ::: "memory");
    __builtin_amdgcn_sched_barrier(0);
    __builtin_amdgcn_s_barrier();
    __builtin_amdgcn_sched_barrier(0);

    bf16x8 af[4][2], bfv[2][2];
    #pragma unroll
    for (int mi = 0; mi < 4; mi++) {
      int row = wm*64 + mi*16 + (lane & 15);
      #pragma unroll
      for (int ks = 0; ks < 2; ks++) {
        int kb = (ks*64 + ((lane >> 4) << 4)) ^ ((row & 7) << 4);
        af[mi][ks] = *(const bf16x8*)((const char*)&As[cur][0] + row*128 + kb);
      }
    }
    #pragma unroll
    for (int ni = 0; ni < 2; ni++) {
      int row = wn*32 + ni*16 + (lane & 15);
      #pragma unroll
      for (int ks = 0; ks < 2; ks++) {
        int kb = (ks*64 + ((lane >> 4) << 4)) ^ ((row & 7) << 4);
        bfv[ni][ks] = *(const bf16x8*)((const char*)&Bs[cur][0] + row*128 + kb);
      }
    }
    #pragma unroll
    for (int ks = 0; ks < 2; ks++)
      #pragma unroll
      for (int mi = 0; mi < 4; mi++)
        #pragma unroll
        for (int ni = 0; ni < 2; ni++)
          acc[mi][ni] = __builtin_amdgcn_mfma_f32_16x16x32_bf16(af[mi][ks], bfv[ni][ks], acc[mi][ni], 0, 0, 0);

    asm volatile("s_waitcnt lgkmcnt(0)" ::: "memory");
    __builtin_amdgcn_sched_barrier(0);
    __builtin_amdgcn_s_barrier();
    __builtin_amdgcn_sched_barrier(0);
    if (t + 2 < NT) STAGE(cur, kbeg + (t + 2) * 64);
  }

  #pragma unroll
  for (int mi = 0; mi < 4; mi++) {
    #pragma unroll
    for (int ni = 0; ni < 2; ni++) {
      int col = n0 + wn*32 + ni*16 + (lane & 15);
      if (MODE == 0) {
        int z = n0 / 768;            // section uniform per block (2304 = 36*64)
        int cc = col - z*768;
        float bvv = (z == 0 ? ba : z == 1 ? bb : bc)[cc];
        #pragma unroll
        for (int r = 0; r < 4; r++) {
          int row = m0 + wm*64 + mi*16 + (lane >> 4)*4 + r;
          Cb[(size_t)z*MM*HH + (size_t)row*HH + cc] = f2b(acc[mi][ni][r] + bvv);
        }
      } else if (MODE == 1) {
        float bvv = ba[col];
        #pragma unroll
        for (int r = 0; r < 4; r++) {
          int row = m0 + wm*64 + mi*16 + (lane >> 4)*4 + r;
          float v = acc[mi][ni][r] + bvv;
          v = 0.5f * v * (1.0f + erff(v * 0.70710678118654752f));
          Cb[(size_t)row*N + col] = f2b(v);
        }
      } else {
        float bvv = (blockIdx.z == 0) ? ba[col] : 0.f;
        #pragma unroll
        for (int r = 0; r < 4; r++) {
          int row = m0 + wm*64 + mi*16 + (lane >> 4)*4 + r;
          Cb[(size_t)blockIdx.z*M*N + (size_t)row*N + col] = f2b(acc[mi][ni][r] + bvv);
        }
      }
    }
  }
}

// ---------------- MFMA flash attention: 4 waves, QBLK=64, dbuf + async-STAGE + defer-max ----------------
__global__ __launch_bounds__(256) void attn_mfma_kernel(
    const ushort* __restrict__ Q, const ushort* __restrict__ Kp, const ushort* __restrict__ Vp,
    ushort* __restrict__ ctx, const int* __restrict__ seg, const int* __restrict__ vl,
    const int* __restrict__ bos)
{
  const int q0 = blockIdx.x * 64;
  const int h  = blockIdx.y;
  const int b  = blockIdx.z;
  const int tid = threadIdx.x;
  const int lane = tid & 63;
  const int wid = tid >> 6;

  __shared__ __align__(16) char Ks[2][8192];
  __shared__ __align__(16) char Vt[2][8192];
  __shared__ __align__(16) char Ps[4][2048];
  __shared__ int segk[2][64];

  const int qrow_frag = q0 + wid*16 + (lane & 15);
  bf16x8 qf[2];
  #pragma unroll
  for (int c = 0; c < 2; c++)
    qf[c] = *(const bf16x8*)&Q[((size_t)(b*LL + qrow_frag))*HH + h*DH + 32*c + (lane >> 4)*8];

  const int vlb  = vl[b];
  const int hist = bos[b*SS];
  int segq[4]; bool qvalid[4], qhist[4];
  #pragma unroll
  for (int r = 0; r < 4; r++) {
    int qg = q0 + wid*16 + (lane >> 4)*4 + r;
    segq[r]   = seg[b*LL + qg];
    qvalid[r] = qg < vlb;
    qhist[r]  = qg < hist;
  }

  float mrow[4], lrow[4];
  #pragma unroll
  for (int r = 0; r < 4; r++) { mrow[r] = -1e30f; lrow[r] = 0.f; }
  f32x4 Oacc[4] = {};

  uint4 kreg0, kreg1, vreg0, vreg1;
  int sreg = 0;

  auto LOADT = [&](int k0) {
    int rk = tid >> 3;
    int c8 = (tid & 7) * 8;
    kreg0 = *(const uint4*)&Kp[((size_t)(b*LL + k0 + rk))*HH + h*DH + c8];
    kreg1 = *(const uint4*)&Kp[((size_t)(b*LL + k0 + rk + 32))*HH + h*DH + c8];
    vreg0 = *(const uint4*)&Vp[((size_t)(b*LL + k0 + lane))*HH + h*DH + wid*8];
    vreg1 = *(const uint4*)&Vp[((size_t)(b*LL + k0 + lane))*HH + h*DH + wid*8 + 32];
    if (tid < 64) sreg = seg[b*LL + k0 + tid];
  };
  auto STORET = [&](int buf) {
    int rk = tid >> 3;
    int c8 = (tid & 7) * 8;
    *(uint4*)(Ks[buf] + (rk*128 + ((c8*2) ^ ((rk & 7) << 4)))) = kreg0;
    int rk2 = rk + 32;
    *(uint4*)(Ks[buf] + (rk2*128 + ((c8*2) ^ ((rk2 & 7) << 4)))) = kreg1;
    const ushort* pv0 = (const ushort*)&vreg0;
    const ushort* pv1 = (const ushort*)&vreg1;
    #pragma unroll
    for (int j = 0; j < 8; j++) {
      int d  = wid*8 + j;
      *(ushort*)(Vt[buf] + (d*128 + ((lane*2) ^ ((d & 7) << 4)))) = pv0[j];
      int d2 = d + 32;
      *(ushort*)(Vt[buf] + (d2*128 + ((lane*2) ^ ((d2 & 7) << 4)))) = pv1[j];
    }
    if (tid < 64) segk[buf][tid] = sreg;
  };

  LOADT(0);
  STORET(0);
  __syncthreads();

  for (int kt = 0; kt < 8; kt++) {
    const int cur = kt & 1;
    const int k0 = kt * 64;
    if (kt < 7) LOADT(k0 + 64);
    __builtin_amdgcn_sched_barrier(0);

    f32x4 sacc[4] = {};
    #pragma unroll
    for (int t = 0; t < 4; t++) {
      int krow = (lane & 15) + 16*t;
      #pragma unroll
      for (int c = 0; c < 2; c++) {
        bf16x8 kf = *(const bf16x8*)(Ks[cur] + (krow*128 +
                      (((32*c + (lane >> 4)*8)*2) ^ ((krow & 7) << 4))));
        sacc[t] = __builtin_amdgcn_mfma_f32_16x16x32_bf16(qf[c], kf, sacc[t], 0, 0, 0);
      }
    }

    #pragma unroll
    for (int t = 0; t < 4; t++) {
      int kg = k0 + (lane & 15) + 16*t;
      bool kvalid = kg < vlb;
      bool khist  = kg < hist;
      int  sk     = segk[cur][(lane & 15) + 16*t];
      #pragma unroll
      for (int r = 0; r < 4; r++) {
        bool ok = qvalid[r] && kvalid && (khist || qhist[r] || (segq[r] == sk));
        sacc[t][r] = sacc[t][r]*0.125f + (ok ? 0.f : -10000.f);
      }
    }

    float scl[4];
    #pragma unroll
    for (int r = 0; r < 4; r++) {
      float rm = fmaxf(fmaxf(sacc[0][r], sacc[1][r]), fmaxf(sacc[2][r], sacc[3][r]));
      rm = fmaxf(rm, __shfl_xor(rm, 1));
      rm = fmaxf(rm, __shfl_xor(rm, 2));
      rm = fmaxf(rm, __shfl_xor(rm, 4));
      rm = fmaxf(rm, __shfl_xor(rm, 8));
      float mnew = (rm > mrow[r] + 8.f) ? rm : mrow[r];
      scl[r] = (mnew == mrow[r]) ? 1.f : __expf(mrow[r] - mnew);
      float rsum = 0.f;
      #pragma unroll
      for (int t = 0; t < 4; t++) {
        float p = __expf(sacc[t][r] - mnew);
        sacc[t][r] = p;
        rsum += p;
      }
      rsum += __shfl_xor(rsum, 1);
      rsum += __shfl_xor(rsum, 2);
      rsum += __shfl_xor(rsum, 4);
      rsum += __shfl_xor(rsum, 8);
      mrow[r] = mnew;
      lrow[r] = lrow[r]*scl[r] + rsum;
    }

    char* Pl = Ps[wid];
    #pragma unroll
    for (int t = 0; t < 4; t++) {
      #pragma unroll
      for (int r = 0; r < 4; r++) {
        int q = (lane >> 4)*4 + r;
        int k = (lane & 15) + 16*t;
        *(ushort*)(Pl + (q*128 + ((k*2) ^ ((q & 7) << 4)))) = f2b(sacc[t][r]);
      }
    }
    asm volatile("s_waitcnt lgkmcnt(0)" ::: "memory");
    bf16x8 pf[2];
    #pragma unroll
    for (int c = 0; c < 2; c++) {
      int q = lane & 15;
      int k = 32*c + (lane >> 4)*8;
      pf[c] = *(const bf16x8*)(Pl + (q*128 + ((k*2) ^ ((q & 7) << 4))));
    }

    bool needscale = (scl[0] != 1.f) | (scl[1] != 1.f) | (scl[2] != 1.f) | (scl[3] != 1.f);
    #pragma unroll
    for (int nt = 0; nt < 4; nt++) {
      if (needscale) {
        #pragma unroll
        for (int r = 0; r < 4; r++) Oacc[nt][r] *= scl[r];
      }
      int d = (lane & 15) + 16*nt;
      #pragma unroll
      for (int c = 0; c < 2; c++) {
        int k = 32*c + (lane >> 4)*8;
        bf16x8 vf = *(const bf16x8*)(Vt[cur] + (d*128 + ((k*2) ^ ((d & 7) << 4))));
        Oacc[nt] = __builtin_amdgcn_mfma_f32_16x16x32_bf16(pf[c], vf, Oacc[nt], 0, 0, 0);
      }
    }

    if (kt < 7) STORET(cur ^ 1);
    __syncthreads();
  }

  #pragma unroll
  for (int nt = 0; nt < 4; nt++) {
    #pragma unroll
    for (int r = 0; r < 4; r++) {
      int q = q0 + wid*16 + (lane >> 4)*4 + r;
      int d = h*DH + (lane & 15) + 16*nt;
      ctx[(size_t)(b*LL + q)*HH + d] = f2b(Oacc[nt][r] / lrow[r]);
    }
  }
}

// ---------------- final pooling (bf16 x) ----------------
__global__ __launch_bounds__(256) void rowdot_kernel(const ushort* __restrict__ x,
                                                     const float* __restrict__ w,
                                                     float* __restrict__ rd) {
  int row = blockIdx.x;
  int t = threadIdx.x;
  float s = 0.f;
  if (t < 192) {
    int c = t << 2;
    ushort4 xv = *(const ushort4*)&x[(size_t)row*HH + c];
    float4 wv = *(const float4*)&w[c];
    s = b2f(xv.x)*wv.x + b2f(xv.y)*wv.y + b2f(xv.z)*wv.z + b2f(xv.w)*wv.w;
  }
  __shared__ float red[256];
  red[t] = s;
  __syncthreads();
  for (int off = 128; off > 0; off >>= 1) {
    if (t < off) red[t] += red[t+off];
    __syncthreads();
  }
  if (t == 0) rd[row] = red[0];
}

__global__ void logits_kernel(const float* __restrict__ rd, const int* __restrict__ bos,
                              const int* __restrict__ vl, const float* __restrict__ fcb,
                              float* __restrict__ out) {
  int i = threadIdx.x;
  if (i >= BB*SS) return;
  int b = i / SS, s = i % SS;
  int start = bos[b*SS + s];
  int end   = (s == SS-1) ? vl[b] : bos[b*SS + s + 1];
  float sum = 0.f;
  for (int t = start; t < end; t++) sum += rd[b*LL + t];
  out[i] = sum / (float)(end - start) + fcb[0];
}

extern "C" void kernel_launch(void* const* d_in, const int* in_sizes, int n_in,
                              void* d_out, int out_size, void* d_ws, size_t ws_size,
                              hipStream_t stream) {
  const float* word_emb  = (const float*)d_in[0];
  const float* pos_emb   = (const float*)d_in[1];
  const float* type_emb  = (const float*)d_in[2];
  const float* emb_ln_g  = (const float*)d_in[3];
  const float* emb_ln_b  = (const float*)d_in[4];
  const float* Wq        = (const float*)d_in[5];
  const float* bq        = (const float*)d_in[6];
  const float* Wk        = (const float*)d_in[7];
  const float* bk        = (const float*)d_in[8];
  const float* Wv        = (const float*)d_in[9];
  const float* bv        = (const float*)d_in[10];
  const float* Wo        = (const float*)d_in[11];
  const float* bo        = (const float*)d_in[12];
  const float* attn_ln_g = (const float*)d_in[13];
  const float* attn_ln_b = (const float*)d_in[14];
  const float* W1        = (const float*)d_in[15];
  const float* b1        = (const float*)d_in[16];
  const float* W2        = (const float*)d_in[17];
  const float* b2        = (const float*)d_in[18];
  const float* ffn_ln_g  = (const float*)d_in[19];
  const float* ffn_ln_b  = (const float*)d_in[20];
  const float* fc_w      = (const float*)d_in[21];
  const float* fc_b      = (const float*)d_in[22];
  const int* input_ids   = (const int*)d_in[23];
  const int* token_type  = (const int*)d_in[24];
  const int* am          = (const int*)d_in[25];
  const int* bos         = (const int*)d_in[26];
  float* out = (float*)d_out;

  char* w = (char*)d_ws;
  ushort* tmpb    = (ushort*)w; w += (size_t)4*MM*HH*2;   // 4 split-K bf16 partials
  ushort* qkv_bf  = (ushort*)w; w += (size_t)3*MM*HH*2;
  ushort* x_bf    = (ushort*)w; w += (size_t)MM*HH*2;
  ushort* ctx_bf  = (ushort*)w; w += (size_t)MM*HH*2;
  ushort* hbuf_bf = (ushort*)w; w += (size_t)MM*FF*2;
  ushort* wbuf    = (ushort*)w; w += (size_t)NL*LWB*2;    // all-layer bf16 weights (blocked tiles)
  float*  rd      = (float*)w;  w += (size_t)MM*4;
  int*    seg     = (int*)w;    w += (size_t)MM*4;
  int*    vl      = (int*)w;    w += 64;

  prep_kernel<<<BB, 512, 0, stream>>>(am, bos, seg, vl);
  convw_all_kernel<<<NL*1728, 256, 0, stream>>>(Wq, Wk, Wv, Wo, W1, W2, wbuf);
  embed_ln_kernel<<<MM, 256, 0, stream>>>(word_emb, pos_emb, type_emb,
                                          emb_ln_g, emb_ln_b, input_ids, token_type, x_bf);

  dim3 gqkv(2304/64, MM/128);       // 36 x 16 = 576 blocks
  dim3 g_ff1(FF/64, MM/128);        // 48 x 16 = 768 blocks
  dim3 g_sk(HH/64, MM/128, 4);      // 12 x 16 x 4 = 768 blocks (split-K4)
  dim3 gattn(LL/64, NH, BB);

  for (int l = 0; l < NL; l++) {
    const ushort* Wqkv_t = wbuf + (size_t)l*LWB;
    const ushort* Wo_t   = wbuf + (size_t)l*LWB + OFF_WO;
    const ushort* W1_t   = wbuf + (size_t)l*LWB + OFF_W1;
    const ushort* W2_t   = wbuf + (size_t)l*LWB + OFF_W2;

    gemm_bt<0><<<gqkv, 256, 0, stream>>>(x_bf, Wqkv_t,
        bq + (size_t)l*HH, bk + (size_t)l*HH, bv + (size_t)l*HH,
        qkv_bf, MM, 2304, HH);

    attn_mfma_kernel<<<gattn, 256, 0, stream>>>(qkv_bf, qkv_bf + (size_t)MM*HH,
                                                qkv_bf + (size_t)2*MM*HH, ctx_bf, seg, vl, bos);

    gemm_bt<2><<<g_sk, 256, 0, stream>>>(ctx_bf, Wo_t,
        bo + (size_t)l*HH, nullptr, nullptr, tmpb, MM, HH, HH);

    add_ln_kernel<4><<<MM, 256, 0, stream>>>(x_bf, tmpb, attn_ln_g + (size_t)l*HH,
                                             attn_ln_b + (size_t)l*HH, x_bf);

    gemm_bt<1><<<g_ff1, 256, 0, stream>>>(x_bf, W1_t,
        b1 + (size_t)l*FF, nullptr, nullptr, hbuf_bf, MM, FF, HH);

    gemm_bt<2><<<g_sk, 256, 0, stream>>>(hbuf_bf, W2_t,
        b2 + (size_t)l*HH, nullptr, nullptr, tmpb, MM, HH, FF);

    add_ln_kernel<4><<<MM, 256, 0, stream>>>(x_bf, tmpb, ffn_ln_g + (size_t)l*HH,
                                             ffn_ln_b + (size_t)l*HH, x_bf);
  }

  rowdot_kernel<<<MM, 256, 0, stream>>>(x_bf, fc_w, rd);
  logits_kernel<<<1, 64, 0, stream>>>(rd, bos, vl, fc_b, out);
}

// Round 20
// 1330.807 us; speedup vs baseline: 1.0708x; 1.0046x over previous
//
#include <hip/hip_runtime.h>
#include <math.h>

#define HH 768
#define FF 3072
#define NL 12
#define NH 12
#define DH 64
#define BB 4
#define LL 512
#define SS 8
#define MM (BB*LL)   // 2048
#define WQSZ (HH*HH)
#define W1SZ (HH*FF)
// per-layer transposed-weight block (elems): QKV(2304x768) Wo(768x768) W1(3072x768) W2(768x3072)
// Layout: blocked tiles [kt][nt][64][64] (8 KB each), natural within tile.
#define LWB 7077888
#define OFF_WO 1769472
#define OFF_W1 2359296
#define OFF_W2 4718592

typedef short bf16x8 __attribute__((ext_vector_type(8)));
typedef float f32x4 __attribute__((ext_vector_type(4)));

__device__ inline ushort f2b(float f) {
  unsigned u = __float_as_uint(f);
  unsigned r = (u + 0x7FFFu + ((u >> 16) & 1u)) >> 16;
  return (ushort)r;
}
__device__ inline float b2f(ushort b) {
  return __uint_as_float(((unsigned)b) << 16);
}

// fast erf (Abramowitz-Stegun 7.1.26, max abs err 1.5e-7)
__device__ inline float fast_gelu(float v) {
  float xr = v * 0.70710678118654752f;
  float ax = fabsf(xr);
  float t  = 1.0f / (1.0f + 0.3275911f * ax);
  float poly = t*(0.254829592f + t*(-0.284496736f + t*(1.421413741f +
               t*(-1.453152027f + t*1.061405429f))));
  float er = 1.0f - poly * __expf(-ax * ax);
  er = (xr < 0.f) ? -er : er;
  return 0.5f * v * (1.0f + er);
}

// bijective XCD swizzle (m204)
__device__ inline void swz_xy(int& x, int& y) {
  int gx = gridDim.x, gy = gridDim.y;
  int flat = blockIdx.x + blockIdx.y * gx;
  int nwg = gx * gy;
  int q = nwg >> 3, r = nwg & 7;
  int xcd = flat & 7, off = flat >> 3;
  int wgid = (xcd < r ? xcd * (q + 1) : r * (q + 1) + (xcd - r) * q) + off;
  x = wgid / gy; y = wgid - x * gy;
}

// ---------------- prep: valid_len, seg ids ----------------
__global__ void prep_kernel(const int* __restrict__ am, const int* __restrict__ bos,
                            int* __restrict__ seg, int* __restrict__ vl) {
  int b = blockIdx.x;
  int t = threadIdx.x;            // 512 threads
  __shared__ int red[512];
  red[t] = am[b*LL + t];
  __syncthreads();
  for (int off = 256; off > 0; off >>= 1) {
    if (t < off) red[t] += red[t+off];
    __syncthreads();
  }
  if (t == 0) vl[b] = red[0];
  int cnt = 0;
  #pragma unroll
  for (int s = 0; s < SS; s++) cnt += (bos[b*SS + s] <= t) ? 1 : 0;
  seg[b*LL + t] = cnt - 1;
}

// ---------------- embedding + LayerNorm -> bf16 x only ----------------
__global__ __launch_bounds__(256) void embed_ln_kernel(
    const float* __restrict__ word_emb, const float* __restrict__ pos_emb,
    const float* __restrict__ type_emb, const float* __restrict__ g,
    const float* __restrict__ bta, const int* __restrict__ ids,
    const int* __restrict__ tts, ushort* __restrict__ xb)
{
  int row = blockIdx.x;           // 0..2047
  int l = row & (LL-1);
  int t = threadIdx.x;
  int id = ids[row];
  int ty = tts[row];
  float4 v = {0.f,0.f,0.f,0.f};
  float s = 0.f, sq = 0.f;
  int c = t << 2;                 // t<192 active
  if (t < 192) {
    float4 a = *(const float4*)&word_emb[(size_t)id*HH + c];
    float4 p = *(const float4*)&pos_emb[l*HH + c];
    float4 ttv = *(const float4*)&type_emb[ty*HH + c];
    v.x = a.x+p.x+ttv.x; v.y = a.y+p.y+ttv.y; v.z = a.z+p.z+ttv.z; v.w = a.w+p.w+ttv.w;
    s = v.x+v.y+v.z+v.w;
    sq = v.x*v.x+v.y*v.y+v.z*v.z+v.w*v.w;
  }
  __shared__ float rs[256], rq[256];
  rs[t] = s; rq[t] = sq;
  __syncthreads();
  for (int off = 128; off > 0; off >>= 1) {
    if (t < off) { rs[t] += rs[t+off]; rq[t] += rq[t+off]; }
    __syncthreads();
  }
  float mean = rs[0] / HH;
  float var  = rq[0] / HH - mean*mean;
  float inv  = rsqrtf(var + 1e-12f);
  if (t < 192) {
    float4 gv = *(const float4*)&g[c];
    float4 bv = *(const float4*)&bta[c];
    ushort4 ob = { f2b((v.x-mean)*inv*gv.x + bv.x),
                   f2b((v.y-mean)*inv*gv.y + bv.y),
                   f2b((v.z-mean)*inv*gv.z + bv.z),
                   f2b((v.w-mean)*inv*gv.w + bv.w) };
    *(ushort4*)&xb[(size_t)row*HH + c] = ob;
  }
}

// ---------------- bf16 residual + NP bf16 partials + LayerNorm -> bf16 ----------------
template<int NP>
__global__ __launch_bounds__(256) void add_ln_kernel(
    const ushort* __restrict__ xin, const ushort* __restrict__ y,
    const float* __restrict__ g, const float* __restrict__ bta,
    ushort* __restrict__ xb)
{
  int row = blockIdx.x;
  int t = threadIdx.x;
  float4 v = {0.f,0.f,0.f,0.f};
  float s = 0.f, sq = 0.f;
  int c = t << 2;
  size_t ix = (size_t)row*HH + c;
  if (t < 192) {
    ushort4 xv = *(const ushort4*)&xin[ix];
    v.x = b2f(xv.x); v.y = b2f(xv.y); v.z = b2f(xv.z); v.w = b2f(xv.w);
    #pragma unroll
    for (int p = 0; p < NP; p++) {
      ushort4 yv = *(const ushort4*)&y[(size_t)p*MM*HH + ix];
      v.x += b2f(yv.x); v.y += b2f(yv.y); v.z += b2f(yv.z); v.w += b2f(yv.w);
    }
    s = v.x+v.y+v.z+v.w;
    sq = v.x*v.x+v.y*v.y+v.z*v.z+v.w*v.w;
  }
  __shared__ float rs[256], rq[256];
  rs[t] = s; rq[t] = sq;
  __syncthreads();
  for (int off = 128; off > 0; off >>= 1) {
    if (t < off) { rs[t] += rs[t+off]; rq[t] += rq[t+off]; }
    __syncthreads();
  }
  float mean = rs[0] / HH;
  float var  = rq[0] / HH - mean*mean;
  float inv  = rsqrtf(var + 1e-12f);
  if (t < 192) {
    float4 gv = *(const float4*)&g[c];
    float4 bv = *(const float4*)&bta[c];
    ushort4 ob = { f2b((v.x-mean)*inv*gv.x + bv.x),
                   f2b((v.y-mean)*inv*gv.y + bv.y),
                   f2b((v.z-mean)*inv*gv.z + bv.z),
                   f2b((v.w-mean)*inv*gv.w + bv.w) };
    *(ushort4*)&xb[ix] = ob;
  }
}

// ---------------- one-time all-layer weight convert + transpose ----------------
// [kt][nt] blocked-tile output. At traffic roofline (~125 us), parked.
__global__ __launch_bounds__(256) void convw_all_kernel(
    const float* __restrict__ Wq, const float* __restrict__ Wk,
    const float* __restrict__ Wv, const float* __restrict__ Wo,
    const float* __restrict__ W1, const float* __restrict__ W2,
    ushort* __restrict__ wbuf)
{
  int idx = blockIdx.x;           // 0..20735
  int l = idx / 1728;
  int t0 = idx % 1728;
  size_t base = (size_t)l * LWB;
  const float* src; ushort* dst; int Nsrc, NTn, k0, n0src, n0dst;
  if (t0 < 432) {            // QKV fused: 36 n-tiles x 12 k-tiles, nt fastest
    int nt = t0 % 36, kt = t0 / 36;
    int z = nt / 12, ntl = nt % 12;
    src = (z == 0 ? Wq : z == 1 ? Wk : Wv) + (size_t)l*WQSZ;
    dst = wbuf + base;
    Nsrc = HH; NTn = 36; k0 = kt*64; n0src = ntl*64; n0dst = nt*64;
  } else if (t0 < 576) {     // Wo: 12 x 12
    int t = t0 - 432; int nt = t % 12, kt = t / 12;
    src = Wo + (size_t)l*WQSZ;
    dst = wbuf + base + OFF_WO;
    Nsrc = HH; NTn = 12; k0 = kt*64; n0src = n0dst = nt*64;
  } else if (t0 < 1152) {    // W1 (768k x 3072n): 48 x 12
    int t = t0 - 576; int nt = t % 48, kt = t / 48;
    src = W1 + (size_t)l*W1SZ;
    dst = wbuf + base + OFF_W1;
    Nsrc = FF; NTn = 48; k0 = kt*64; n0src = n0dst = nt*64;
  } else {                   // W2 (3072k x 768n): 12 x 48
    int t = t0 - 1152; int nt = t % 12, kt = t / 12;
    src = W2 + (size_t)l*W1SZ;
    dst = wbuf + base + OFF_W2;
    Nsrc = HH; NTn = 12; k0 = kt*64; n0src = n0dst = nt*64;
  }
  __shared__ ushort tt[64][66];   // PAD=66: row stride 132 B
  int tid = threadIdx.x;
  int kr = tid >> 4;              // 0..15
  int nn0 = (tid & 15) << 2;      // 0,4,...,60
  #pragma unroll
  for (int i = 0; i < 4; i++) {
    int k = kr + i*16;
    float4 v = *(const float4*)&src[(size_t)(k0+k)*Nsrc + n0src + nn0];
    ushort2 lo = { f2b(v.x), f2b(v.y) };
    ushort2 hi = { f2b(v.z), f2b(v.w) };
    *(ushort2*)&tt[k][nn0]     = lo;
    *(ushort2*)&tt[k][nn0 + 2] = hi;
  }
  __syncthreads();
  ushort* dtile = dst + ((size_t)(k0 >> 6)*NTn + (n0dst >> 6)) * 4096;
  #pragma unroll
  for (int it = 0; it < 2; it++) {
    int n  = it*32 + (tid >> 3);  // 0..63
    int kc = (tid & 7) << 3;      // 0,8,...,56
    ushort tmp8[8];
    #pragma unroll
    for (int j = 0; j < 8; j++) tmp8[j] = tt[kc + j][n];
    *(uint4*)&dtile[n*64 + kc] = *(const uint4*)tmp8;
  }
}

// ---------------- bf16 MFMA GEMM, 128x64 tile, BK=64, 2-buffer counted-vmcnt pipeline ----------------
// B operand in blocked-tile layout [kt][nt][64][64].
// MODE 0: QKV fused (N=2304), bf16 out split to 3 buffers, per-section bias
// MODE 1: bf16 out + bias + GELU (FF1, fast erf)
// MODE 2: bf16 partial out (splitK4 via blockIdx.z), bias at z==0 (Wo, FF2)
template<int MODE>
__global__ __launch_bounds__(256) void gemm_bt(
    const ushort* __restrict__ A, const ushort* __restrict__ Bt,
    const float* __restrict__ ba, const float* __restrict__ bb,
    const float* __restrict__ bc, ushort* __restrict__ Cb,
    int M, int N, int K)
{
  __shared__ __align__(16) ushort As[2][128*64];
  __shared__ __align__(16) ushort Bs[2][64*64];
  const int tid = threadIdx.x;
  const int lane = tid & 63, wid = tid >> 6;
  const int wm = wid >> 1, wn = wid & 1;
  int bx, by; swz_xy(bx, by);
  const int m0 = by * 128, n0 = bx * 64;
  int kbeg = 0, kcnt = K;
  if (MODE == 2) { kcnt = K >> 2; kbeg = blockIdx.z * kcnt; }
  const int NT = kcnt >> 6;
  const int ntiles = N >> 6;

  auto STAGE = [&](int buf, int k0) {
    #pragma unroll
    for (int j = 0; j < 4; j++) {
      int c = j*256 + tid;
      int r = c >> 3;
      int kk = ((c & 7) ^ (r & 7)) << 3;
      __builtin_amdgcn_global_load_lds(
        (const __attribute__((address_space(1))) void*)(A + (size_t)(m0+r)*K + k0 + kk),
        (__attribute__((address_space(3))) void*)(&As[buf][c*8]), 16, 0, 0);
    }
    const ushort* btile = Bt + ((size_t)(k0 >> 6) * ntiles + (n0 >> 6)) * 4096;
    #pragma unroll
    for (int j = 0; j < 2; j++) {
      int c = j*256 + tid;
      int r = c >> 3;
      int kk = ((c & 7) ^ (r & 7)) << 3;
      __builtin_amdgcn_global_load_lds(
        (const __attribute__((address_space(1))) void*)(btile + r*64 + kk),
        (__attribute__((address_space(3))) void*)(&Bs[buf][c*8]), 16, 0, 0);
    }
  };

  f32x4 acc[4][2] = {};
  STAGE(0, kbeg);
  if (NT > 1) STAGE(1, kbeg + 64);
  for (int t = 0; t < NT; ++t) {
    const int cur = t & 1;
    if (t + 1 < NT) asm volatile("s_waitcnt vmcnt(6)" ::: "memory");
    else            asm volatile("s_waitcnt vmcnt(0)" ::: "memory");
    __builtin_amdgcn_sched_barrier(0);
    __builtin_amdgcn_s_barrier();
    __builtin_amdgcn_sched_barrier(0);

    bf16x8 af[4][2], bfv[2][2];
    #pragma unroll
    for (int mi = 0; mi < 4; mi++) {
      int row = wm*64 + mi*16 + (lane & 15);
      #pragma unroll
      for (int ks = 0; ks < 2; ks++) {
        int kb = (ks*64 + ((lane >> 4) << 4)) ^ ((row & 7) << 4);
        af[mi][ks] = *(const bf16x8*)((const char*)&As[cur][0] + row*128 + kb);
      }
    }
    #pragma unroll
    for (int ni = 0; ni < 2; ni++) {
      int row = wn*32 + ni*16 + (lane & 15);
      #pragma unroll
      for (int ks = 0; ks < 2; ks++) {
        int kb = (ks*64 + ((lane >> 4) << 4)) ^ ((row & 7) << 4);
        bfv[ni][ks] = *(const bf16x8*)((const char*)&Bs[cur][0] + row*128 + kb);
      }
    }
    #pragma unroll
    for (int ks = 0; ks < 2; ks++)
      #pragma unroll
      for (int mi = 0; mi < 4; mi++)
        #pragma unroll
        for (int ni = 0; ni < 2; ni++)
          acc[mi][ni] = __builtin_amdgcn_mfma_f32_16x16x32_bf16(af[mi][ks], bfv[ni][ks], acc[mi][ni], 0, 0, 0);

    asm volatile("s_waitcnt lgkmcnt(0)" ::: "memory");
    __builtin_amdgcn_sched_barrier(0);
    __builtin_amdgcn_s_barrier();
    __builtin_amdgcn_sched_barrier(0);
    if (t + 2 < NT) STAGE(cur, kbeg + (t + 2) * 64);
  }

  #pragma unroll
  for (int mi = 0; mi < 4; mi++) {
    #pragma unroll
    for (int ni = 0; ni < 2; ni++) {
      int col = n0 + wn*32 + ni*16 + (lane & 15);
      if (MODE == 0) {
        int z = n0 / 768;            // section uniform per block (2304 = 36*64)
        int cc = col - z*768;
        float bvv = (z == 0 ? ba : z == 1 ? bb : bc)[cc];
        #pragma unroll
        for (int r = 0; r < 4; r++) {
          int row = m0 + wm*64 + mi*16 + (lane >> 4)*4 + r;
          Cb[(size_t)z*MM*HH + (size_t)row*HH + cc] = f2b(acc[mi][ni][r] + bvv);
        }
      } else if (MODE == 1) {
        float bvv = ba[col];
        #pragma unroll
        for (int r = 0; r < 4; r++) {
          int row = m0 + wm*64 + mi*16 + (lane >> 4)*4 + r;
          Cb[(size_t)row*N + col] = f2b(fast_gelu(acc[mi][ni][r] + bvv));
        }
      } else {
        float bvv = (blockIdx.z == 0) ? ba[col] : 0.f;
        #pragma unroll
        for (int r = 0; r < 4; r++) {
          int row = m0 + wm*64 + mi*16 + (lane >> 4)*4 + r;
          Cb[(size_t)blockIdx.z*M*N + (size_t)row*N + col] = f2b(acc[mi][ni][r] + bvv);
        }
      }
    }
  }
}

// ---------------- MFMA flash attention: 4 waves, QBLK=64, dbuf + async-STAGE + defer-max ----------------
__global__ __launch_bounds__(256) void attn_mfma_kernel(
    const ushort* __restrict__ Q, const ushort* __restrict__ Kp, const ushort* __restrict__ Vp,
    ushort* __restrict__ ctx, const int* __restrict__ seg, const int* __restrict__ vl,
    const int* __restrict__ bos)
{
  const int q0 = blockIdx.x * 64;
  const int h  = blockIdx.y;
  const int b  = blockIdx.z;
  const int tid = threadIdx.x;
  const int lane = tid & 63;
  const int wid = tid >> 6;

  __shared__ __align__(16) char Ks[2][8192];
  __shared__ __align__(16) char Vt[2][8192];
  __shared__ __align__(16) char Ps[4][2048];
  __shared__ int segk[2][64];

  const int qrow_frag = q0 + wid*16 + (lane & 15);
  bf16x8 qf[2];
  #pragma unroll
  for (int c = 0; c < 2; c++)
    qf[c] = *(const bf16x8*)&Q[((size_t)(b*LL + qrow_frag))*HH + h*DH + 32*c + (lane >> 4)*8];

  const int vlb  = vl[b];
  const int hist = bos[b*SS];
  int segq[4]; bool qvalid[4], qhist[4];
  #pragma unroll
  for (int r = 0; r < 4; r++) {
    int qg = q0 + wid*16 + (lane >> 4)*4 + r;
    segq[r]   = seg[b*LL + qg];
    qvalid[r] = qg < vlb;
    qhist[r]  = qg < hist;
  }

  float mrow[4], lrow[4];
  #pragma unroll
  for (int r = 0; r < 4; r++) { mrow[r] = -1e30f; lrow[r] = 0.f; }
  f32x4 Oacc[4] = {};

  uint4 kreg0, kreg1, vreg0, vreg1;
  int sreg = 0;

  auto LOADT = [&](int k0) {
    int rk = tid >> 3;
    int c8 = (tid & 7) * 8;
    kreg0 = *(const uint4*)&Kp[((size_t)(b*LL + k0 + rk))*HH + h*DH + c8];
    kreg1 = *(const uint4*)&Kp[((size_t)(b*LL + k0 + rk + 32))*HH + h*DH + c8];
    vreg0 = *(const uint4*)&Vp[((size_t)(b*LL + k0 + lane))*HH + h*DH + wid*8];
    vreg1 = *(const uint4*)&Vp[((size_t)(b*LL + k0 + lane))*HH + h*DH + wid*8 + 32];
    if (tid < 64) sreg = seg[b*LL + k0 + tid];
  };
  auto STORET = [&](int buf) {
    int rk = tid >> 3;
    int c8 = (tid & 7) * 8;
    *(uint4*)(Ks[buf] + (rk*128 + ((c8*2) ^ ((rk & 7) << 4)))) = kreg0;
    int rk2 = rk + 32;
    *(uint4*)(Ks[buf] + (rk2*128 + ((c8*2) ^ ((rk2 & 7) << 4)))) = kreg1;
    const ushort* pv0 = (const ushort*)&vreg0;
    const ushort* pv1 = (const ushort*)&vreg1;
    #pragma unroll
    for (int j = 0; j < 8; j++) {
      int d  = wid*8 + j;
      *(ushort*)(Vt[buf] + (d*128 + ((lane*2) ^ ((d & 7) << 4)))) = pv0[j];
      int d2 = d + 32;
      *(ushort*)(Vt[buf] + (d2*128 + ((lane*2) ^ ((d2 & 7) << 4)))) = pv1[j];
    }
    if (tid < 64) segk[buf][tid] = sreg;
  };

  LOADT(0);
  STORET(0);
  __syncthreads();

  for (int kt = 0; kt < 8; kt++) {
    const int cur = kt & 1;
    const int k0 = kt * 64;
    if (kt < 7) LOADT(k0 + 64);
    __builtin_amdgcn_sched_barrier(0);

    f32x4 sacc[4] = {};
    #pragma unroll
    for (int t = 0; t < 4; t++) {
      int krow = (lane & 15) + 16*t;
      #pragma unroll
      for (int c = 0; c < 2; c++) {
        bf16x8 kf = *(const bf16x8*)(Ks[cur] + (krow*128 +
                      (((32*c + (lane >> 4)*8)*2) ^ ((krow & 7) << 4))));
        sacc[t] = __builtin_amdgcn_mfma_f32_16x16x32_bf16(qf[c], kf, sacc[t], 0, 0, 0);
      }
    }

    #pragma unroll
    for (int t = 0; t < 4; t++) {
      int kg = k0 + (lane & 15) + 16*t;
      bool kvalid = kg < vlb;
      bool khist  = kg < hist;
      int  sk     = segk[cur][(lane & 15) + 16*t];
      #pragma unroll
      for (int r = 0; r < 4; r++) {
        bool ok = qvalid[r] && kvalid && (khist || qhist[r] || (segq[r] == sk));
        sacc[t][r] = sacc[t][r]*0.125f + (ok ? 0.f : -10000.f);
      }
    }

    float scl[4];
    #pragma unroll
    for (int r = 0; r < 4; r++) {
      float rm = fmaxf(fmaxf(sacc[0][r], sacc[1][r]), fmaxf(sacc[2][r], sacc[3][r]));
      rm = fmaxf(rm, __shfl_xor(rm, 1));
      rm = fmaxf(rm, __shfl_xor(rm, 2));
      rm = fmaxf(rm, __shfl_xor(rm, 4));
      rm = fmaxf(rm, __shfl_xor(rm, 8));
      float mnew = (rm > mrow[r] + 8.f) ? rm : mrow[r];
      scl[r] = (mnew == mrow[r]) ? 1.f : __expf(mrow[r] - mnew);
      float rsum = 0.f;
      #pragma unroll
      for (int t = 0; t < 4; t++) {
        float p = __expf(sacc[t][r] - mnew);
        sacc[t][r] = p;
        rsum += p;
      }
      rsum += __shfl_xor(rsum, 1);
      rsum += __shfl_xor(rsum, 2);
      rsum += __shfl_xor(rsum, 4);
      rsum += __shfl_xor(rsum, 8);
      mrow[r] = mnew;
      lrow[r] = lrow[r]*scl[r] + rsum;
    }

    char* Pl = Ps[wid];
    #pragma unroll
    for (int t = 0; t < 4; t++) {
      #pragma unroll
      for (int r = 0; r < 4; r++) {
        int q = (lane >> 4)*4 + r;
        int k = (lane & 15) + 16*t;
        *(ushort*)(Pl + (q*128 + ((k*2) ^ ((q & 7) << 4)))) = f2b(sacc[t][r]);
      }
    }
    asm volatile("s_waitcnt lgkmcnt(0)" ::: "memory");
    bf16x8 pf[2];
    #pragma unroll
    for (int c = 0; c < 2; c++) {
      int q = lane & 15;
      int k = 32*c + (lane >> 4)*8;
      pf[c] = *(const bf16x8*)(Pl + (q*128 + ((k*2) ^ ((q & 7) << 4))));
    }

    bool needscale = (scl[0] != 1.f) | (scl[1] != 1.f) | (scl[2] != 1.f) | (scl[3] != 1.f);
    #pragma unroll
    for (int nt = 0; nt < 4; nt++) {
      if (needscale) {
        #pragma unroll
        for (int r = 0; r < 4; r++) Oacc[nt][r] *= scl[r];
      }
      int d = (lane & 15) + 16*nt;
      #pragma unroll
      for (int c = 0; c < 2; c++) {
        int k = 32*c + (lane >> 4)*8;
        bf16x8 vf = *(const bf16x8*)(Vt[cur] + (d*128 + ((k*2) ^ ((d & 7) << 4))));
        Oacc[nt] = __builtin_amdgcn_mfma_f32_16x16x32_bf16(pf[c], vf, Oacc[nt], 0, 0, 0);
      }
    }

    if (kt < 7) STORET(cur ^ 1);
    __syncthreads();
  }

  #pragma unroll
  for (int nt = 0; nt < 4; nt++) {
    #pragma unroll
    for (int r = 0; r < 4; r++) {
      int q = q0 + wid*16 + (lane >> 4)*4 + r;
      int d = h*DH + (lane & 15) + 16*nt;
      ctx[(size_t)(b*LL + q)*HH + d] = f2b(Oacc[nt][r] / lrow[r]);
    }
  }
}

// ---------------- final pooling (bf16 x) ----------------
__global__ __launch_bounds__(256) void rowdot_kernel(const ushort* __restrict__ x,
                                                     const float* __restrict__ w,
                                                     float* __restrict__ rd) {
  int row = blockIdx.x;
  int t = threadIdx.x;
  float s = 0.f;
  if (t < 192) {
    int c = t << 2;
    ushort4 xv = *(const ushort4*)&x[(size_t)row*HH + c];
    float4 wv = *(const float4*)&w[c];
    s = b2f(xv.x)*wv.x + b2f(xv.y)*wv.y + b2f(xv.z)*wv.z + b2f(xv.w)*wv.w;
  }
  __shared__ float red[256];
  red[t] = s;
  __syncthreads();
  for (int off = 128; off > 0; off >>= 1) {
    if (t < off) red[t] += red[t+off];
    __syncthreads();
  }
  if (t == 0) rd[row] = red[0];
}

__global__ void logits_kernel(const float* __restrict__ rd, const int* __restrict__ bos,
                              const int* __restrict__ vl, const float* __restrict__ fcb,
                              float* __restrict__ out) {
  int i = threadIdx.x;
  if (i >= BB*SS) return;
  int b = i / SS, s = i % SS;
  int start = bos[b*SS + s];
  int end   = (s == SS-1) ? vl[b] : bos[b*SS + s + 1];
  float sum = 0.f;
  for (int t = start; t < end; t++) sum += rd[b*LL + t];
  out[i] = sum / (float)(end - start) + fcb[0];
}

extern "C" void kernel_launch(void* const* d_in, const int* in_sizes, int n_in,
                              void* d_out, int out_size, void* d_ws, size_t ws_size,
                              hipStream_t stream) {
  const float* word_emb  = (const float*)d_in[0];
  const float* pos_emb   = (const float*)d_in[1];
  const float* type_emb  = (const float*)d_in[2];
  const float* emb_ln_g  = (const float*)d_in[3];
  const float* emb_ln_b  = (const float*)d_in[4];
  const float* Wq        = (const float*)d_in[5];
  const float* bq        = (const float*)d_in[6];
  const float* Wk        = (const float*)d_in[7];
  const float* bk        = (const float*)d_in[8];
  const float* Wv        = (const float*)d_in[9];
  const float* bv        = (const float*)d_in[10];
  const float* Wo        = (const float*)d_in[11];
  const float* bo        = (const float*)d_in[12];
  const float* attn_ln_g = (const float*)d_in[13];
  const float* attn_ln_b = (const float*)d_in[14];
  const float* W1        = (const float*)d_in[15];
  const float* b1        = (const float*)d_in[16];
  const float* W2        = (const float*)d_in[17];
  const float* b2        = (const float*)d_in[18];
  const float* ffn_ln_g  = (const float*)d_in[19];
  const float* ffn_ln_b  = (const float*)d_in[20];
  const float* fc_w      = (const float*)d_in[21];
  const float* fc_b      = (const float*)d_in[22];
  const int* input_ids   = (const int*)d_in[23];
  const int* token_type  = (const int*)d_in[24];
  const int* am          = (const int*)d_in[25];
  const int* bos         = (const int*)d_in[26];
  float* out = (float*)d_out;

  char* w = (char*)d_ws;
  ushort* tmpb    = (ushort*)w; w += (size_t)4*MM*HH*2;   // 4 split-K bf16 partials
  ushort* qkv_bf  = (ushort*)w; w += (size_t)3*MM*HH*2;
  ushort* x_bf    = (ushort*)w; w += (size_t)MM*HH*2;
  ushort* ctx_bf  = (ushort*)w; w += (size_t)MM*HH*2;
  ushort* hbuf_bf = (ushort*)w; w += (size_t)MM*FF*2;
  ushort* wbuf    = (ushort*)w; w += (size_t)NL*LWB*2;    // all-layer bf16 weights (blocked tiles)
  float*  rd      = (float*)w;  w += (size_t)MM*4;
  int*    seg     = (int*)w;    w += (size_t)MM*4;
  int*    vl      = (int*)w;    w += 64;

  prep_kernel<<<BB, 512, 0, stream>>>(am, bos, seg, vl);
  convw_all_kernel<<<NL*1728, 256, 0, stream>>>(Wq, Wk, Wv, Wo, W1, W2, wbuf);
  embed_ln_kernel<<<MM, 256, 0, stream>>>(word_emb, pos_emb, type_emb,
                                          emb_ln_g, emb_ln_b, input_ids, token_type, x_bf);

  dim3 gqkv(2304/64, MM/128);       // 36 x 16 = 576 blocks
  dim3 g_ff1(FF/64, MM/128);        // 48 x 16 = 768 blocks
  dim3 g_sk(HH/64, MM/128, 4);      // 12 x 16 x 4 = 768 blocks (split-K4)
  dim3 gattn(LL/64, NH, BB);

  for (int l = 0; l < NL; l++) {
    const ushort* Wqkv_t = wbuf + (size_t)l*LWB;
    const ushort* Wo_t   = wbuf + (size_t)l*LWB + OFF_WO;
    const ushort* W1_t   = wbuf + (size_t)l*LWB + OFF_W1;
    const ushort* W2_t   = wbuf + (size_t)l*LWB + OFF_W2;

    gemm_bt<0><<<gqkv, 256, 0, stream>>>(x_bf, Wqkv_t,
        bq + (size_t)l*HH, bk + (size_t)l*HH, bv + (size_t)l*HH,
        qkv_bf, MM, 2304, HH);

    attn_mfma_kernel<<<gattn, 256, 0, stream>>>(qkv_bf, qkv_bf + (size_t)MM*HH,
                                                qkv_bf + (size_t)2*MM*HH, ctx_bf, seg, vl, bos);

    gemm_bt<2><<<g_sk, 256, 0, stream>>>(ctx_bf, Wo_t,
        bo + (size_t)l*HH, nullptr, nullptr, tmpb, MM, HH, HH);

    add_ln_kernel<4><<<MM, 256, 0, stream>>>(x_bf, tmpb, attn_ln_g + (size_t)l*HH,
                                             attn_ln_b + (size_t)l*HH, x_bf);

    gemm_bt<1><<<g_ff1, 256, 0, stream>>>(x_bf, W1_t,
        b1 + (size_t)l*FF, nullptr, nullptr, hbuf_bf, MM, FF, HH);

    gemm_bt<2><<<g_sk, 256, 0, stream>>>(hbuf_bf, W2_t,
        b2 + (size_t)l*HH, nullptr, nullptr, tmpb, MM, HH, FF);

    add_ln_kernel<4><<<MM, 256, 0, stream>>>(x_bf, tmpb, ffn_ln_g + (size_t)l*HH,
                                             ffn_ln_b + (size_t)l*HH, x_bf);
  }

  rowdot_kernel<<<MM, 256, 0, stream>>>(x_bf, fc_w, rd);
  logits_kernel<<<1, 64, 0, stream>>>(rd, bos, vl, fc_b, out);
}